// Round 1
// baseline (156.160 us; speedup 1.0000x reference)
//
#include <hip/hip_runtime.h>
#include <math.h>

#define B_DIM 256
#define M_DIM 4096
#define EPSV 1e-7f

// ws layout (doubles):
// 0: coord_num, 1: width_num, 2: validity_sum, 3: n_valid, 4: cont_sum, 5: recon_sum

__global__ __launch_bounds__(1024) void main_loss_kernel(
    const float* __restrict__ pred, const float* __restrict__ tgt,
    double* __restrict__ ws)
{
    __shared__ float s_p4[M_DIM];                     // 16 KB
    __shared__ float s_p5[M_DIM];                     // 16 KB
    __shared__ unsigned long long s_words[M_DIM / 64]; // 64 words = 512 B
    __shared__ float s_red[16][5];

    const int b    = blockIdx.x;
    const int t    = threadIdx.x;
    const int lane = t & 63;
    const int wave = t >> 6;   // 0..15

    const float* prow = pred + (size_t)b * M_DIM * 9;
    const float* trow = tgt  + (size_t)b * M_DIM * 9;

    float coord_s = 0.f, width_s = 0.f, val_s = 0.f, nval_s = 0.f;
    bool valid_k[4];

    #pragma unroll
    for (int k = 0; k < 4; ++k) {
        const int m = k * 1024 + t;
        const float* p = prow + m * 9;
        const float* q = trow + m * 9;
        float p0 = p[0], p1 = p[1], p2 = p[2], p3 = p[3], p4 = p[4],
              p5 = p[5], p6 = p[6], p7 = p[7], p8 = p[8];
        float t0 = q[0], t1 = q[1], t2 = q[2], t3 = q[3], t4 = q[4],
              t5 = q[5], t6 = q[6], t7 = q[7], t8 = q[8];

        bool valid = (t8 > 0.5f);
        float fm = valid ? 1.f : 0.f;
        coord_s += fm * (fabsf(p0 - t0) + fabsf(p1 - t1) + fabsf(p2 - t2) +
                         fabsf(p3 - t3) + fabsf(p4 - t4) + fabsf(p5 - t5));
        width_s += fm * (fabsf(p6 - t6) + fabsf(p7 - t7));
        nval_s  += fm;

        float pc = fminf(fmaxf(p8, EPSV), 1.0f - EPSV);
        val_s += -(t8 * logf(pc) + (1.0f - t8) * logf(1.0f - pc));

        s_p4[m] = p4;
        s_p5[m] = p5;
        valid_k[k] = valid;

        unsigned long long bal = __ballot(valid);
        if (lane == 0) s_words[k * 16 + wave] = bal;  // word index = m>>6
    }
    __syncthreads();

    // Continuity: consecutive-valid-pair distances via bitmask scan.
    float cont_s = 0.f;
    #pragma unroll
    for (int k = 0; k < 4; ++k) {
        if (!valid_k[k]) continue;
        const int m   = k * 1024 + t;
        const int w   = m >> 6;
        const int bit = m & 63;
        unsigned long long mask = s_words[w];
        mask &= (bit == 63) ? 0ULL : (~0ULL << (bit + 1));
        int nxt = -1;
        if (mask) {
            nxt = (w << 6) + __builtin_ctzll(mask);
        } else {
            for (int w2 = w + 1; w2 < (M_DIM / 64); ++w2) {
                unsigned long long mw = s_words[w2];
                if (mw) { nxt = (w2 << 6) + __builtin_ctzll(mw); break; }
            }
        }
        if (nxt >= 0) {
            cont_s += 0.5f * (fabsf(s_p4[m] - s_p4[nxt]) +
                              fabsf(s_p5[m] - s_p5[nxt]));
        }
    }

    // Block reduction of 5 partials.
    float vals[5] = {coord_s, width_s, val_s, nval_s, cont_s};
    #pragma unroll
    for (int i = 0; i < 5; ++i) {
        float v = vals[i];
        #pragma unroll
        for (int off = 32; off > 0; off >>= 1) v += __shfl_down(v, off, 64);
        vals[i] = v;
    }
    if (lane == 0) {
        #pragma unroll
        for (int i = 0; i < 5; ++i) s_red[wave][i] = vals[i];
    }
    __syncthreads();
    if (t == 0) {
        float acc[5] = {0.f, 0.f, 0.f, 0.f, 0.f};
        for (int wv = 0; wv < 16; ++wv)
            #pragma unroll
            for (int i = 0; i < 5; ++i) acc[i] += s_red[wv][i];
        atomicAdd(&ws[0], (double)acc[0]);
        atomicAdd(&ws[1], (double)acc[1]);
        atomicAdd(&ws[2], (double)acc[2]);
        atomicAdd(&ws[3], (double)acc[3]);
        atomicAdd(&ws[4], (double)acc[4]);
    }
}

__global__ __launch_bounds__(256) void recon_kernel(
    const float4* __restrict__ rec, const float4* __restrict__ img,
    double* __restrict__ ws, int n4)
{
    int idx    = blockIdx.x * blockDim.x + threadIdx.x;
    int stride = gridDim.x * blockDim.x;
    float s = 0.f;
    for (int i = idx; i < n4; i += stride) {
        float4 r  = rec[i];
        float4 im = img[i];
        float d0 = r.x - im.x, d1 = r.y - im.y, d2 = r.z - im.z, d3 = r.w - im.w;
        s += d0 * d0 + d1 * d1 + d2 * d2 + d3 * d3;
    }
    #pragma unroll
    for (int off = 32; off > 0; off >>= 1) s += __shfl_down(s, off, 64);
    __shared__ float sred[4];
    int lane = threadIdx.x & 63, wave = threadIdx.x >> 6;
    if (lane == 0) sred[wave] = s;
    __syncthreads();
    if (threadIdx.x == 0) {
        float a = sred[0] + sred[1] + sred[2] + sred[3];
        atomicAdd(&ws[5], (double)a);
    }
}

__global__ void finalize_kernel(const double* __restrict__ ws,
                                float* __restrict__ out)
{
    double coord_num = ws[0];
    double width_num = ws[1];
    double val_sum   = ws[2];
    double nv        = ws[3];
    double cont      = ws[4];
    double recon     = ws[5];

    double coord = (nv > 0.0) ? coord_num / fmax(nv * 6.0, 1.0) : 0.0;
    double width = (nv > 0.0) ? width_num / fmax(nv * 2.0, 1.0) : 0.0;
    double validity = val_sum / ((double)B_DIM * (double)M_DIM);
    double contl    = cont / (double)B_DIM;
    double reconl   = recon / ((double)B_DIM * 128.0 * 128.0);

    out[0] = (float)(coord + width + 2.0 * validity + 0.2 * contl + 0.1 * reconl);
}

extern "C" void kernel_launch(void* const* d_in, const int* in_sizes, int n_in,
                              void* d_out, int out_size, void* d_ws, size_t ws_size,
                              hipStream_t stream) {
    const float* pred = (const float*)d_in[0];
    const float* tgt  = (const float*)d_in[1];
    const float* rec  = (const float*)d_in[2];
    const float* img  = (const float*)d_in[3];
    double* ws = (double*)d_ws;

    hipMemsetAsync(d_ws, 0, 6 * sizeof(double), stream);

    main_loss_kernel<<<B_DIM, 1024, 0, stream>>>(pred, tgt, ws);

    const int n4 = (B_DIM * 128 * 128) / 4;  // float4 count
    recon_kernel<<<1024, 256, 0, stream>>>((const float4*)rec, (const float4*)img, ws, n4);

    finalize_kernel<<<1, 1, 0, stream>>>(ws, (float*)d_out);
}